// Round 9
// baseline (486.178 us; speedup 1.0000x reference)
//
#include <hip/hip_runtime.h>

// Problem constants
#define B_    2
#define S_    2048
#define D_    1024
#define H_    16
#define DK_   64
#define DFF_  4096
#define MROWS (B_*S_)   // 4096 rows

typedef float f32x4 __attribute__((ext_vector_type(4)));
typedef __bf16 bf16x8 __attribute__((ext_vector_type(8)));

static __device__ __forceinline__ unsigned short f2bf(float f) {
    union { __bf16 h; unsigned short u; } cv;
    cv.h = (__bf16)f;
    return cv.u;
}

// async global->LDS, 16B per lane; LDS base must be wave-uniform (HW: base + lane*16)
static __device__ __forceinline__ void gload16(const unsigned short* g, unsigned short* l) {
    __builtin_amdgcn_global_load_lds((const __attribute__((address_space(1))) void*)g,
                                     (__attribute__((address_space(3))) void*)l, 16, 0, 0);
}

// ---------------------------------------------------------------- prep: all weight casts + bias concat (1 launch)
__global__ __launch_bounds__(256) void prep_kernel(
    const float* __restrict__ wq, const float* __restrict__ wk,
    const float* __restrict__ wv, const float* __restrict__ wo,
    const float* __restrict__ w1, const float* __restrict__ w2,
    const float* __restrict__ bq, const float* __restrict__ bk,
    unsigned short* __restrict__ wqkb, unsigned short* __restrict__ wvb,
    unsigned short* __restrict__ wob, unsigned short* __restrict__ w1b,
    unsigned short* __restrict__ w2b, float* __restrict__ bqk) {
    int blk = blockIdx.x;
    if (blk >= 12288) {               // bias concat: bqk[0..1023]=bq, [1024..2047]=bk
        int t0 = threadIdx.x * 8;
        #pragma unroll
        for (int i = 0; i < 8; i++) {
            int j = t0 + i;
            bqk[j] = (j < 1024) ? bq[j] : bk[j - 1024];
        }
        return;
    }
    const float* src; unsigned short* dst; int lb;
    if      (blk < 1024) { src = wq; dst = wqkb;             lb = blk;        }
    else if (blk < 2048) { src = wk; dst = wqkb + (1 << 20); lb = blk - 1024; }
    else if (blk < 3072) { src = wv; dst = wvb;              lb = blk - 2048; }
    else if (blk < 4096) { src = wo; dst = wob;              lb = blk - 3072; }
    else if (blk < 8192) { src = w1; dst = w1b;              lb = blk - 4096; }
    else                 { src = w2; dst = w2b;              lb = blk - 8192; }
    int i4 = lb * 256 + threadIdx.x;
    float4 v = ((const float4*)src)[i4];
    ushort4 o;
    o.x = f2bf(v.x); o.y = f2bf(v.y); o.z = f2bf(v.z); o.w = f2bf(v.w);
    ((ushort4*)dst)[i4] = o;
}

// ---------------------------------------------------------------- LayerNorm (ddof=1, /(std+eps))
__global__ __launch_bounds__(256) void ln_kernel(const float* __restrict__ x,
                                                 const float* __restrict__ alphap,
                                                 const float* __restrict__ betap,
                                                 unsigned short* __restrict__ out) {
    int row = blockIdx.x;
    int t = threadIdx.x;
    const float* xr = x + (size_t)row * D_;
    float4 v = ((const float4*)xr)[t];
    float s  = v.x + v.y + v.z + v.w;
    float s2 = v.x*v.x + v.y*v.y + v.z*v.z + v.w*v.w;
    #pragma unroll
    for (int o = 1; o < 64; o <<= 1) { s += __shfl_xor(s, o); s2 += __shfl_xor(s2, o); }
    __shared__ float ss[4], ss2[4];
    if ((t & 63) == 0) { ss[t >> 6] = s; ss2[t >> 6] = s2; }
    __syncthreads();
    float S  = ss[0] + ss[1] + ss[2] + ss[3];
    float S2 = ss2[0] + ss2[1] + ss2[2] + ss2[3];
    float mean = S * (1.f / (float)D_);
    float var  = (S2 - S * mean) / (float)(D_ - 1);   // unbiased (ddof=1)
    float alpha = alphap[0], beta = betap[0];
    float inv = alpha / (sqrtf(fmaxf(var, 0.f)) + 1e-6f);
    ushort4 o4;
    o4.x = f2bf((v.x - mean) * inv + beta);
    o4.y = f2bf((v.y - mean) * inv + beta);
    o4.z = f2bf((v.z - mean) * inv + beta);
    o4.w = f2bf((v.w - mean) * inv + beta);
    ((ushort4*)(out + (size_t)row * D_))[t] = o4;
}

// ---------------------------------------------------------------- 2-phase GEMM body (m97 structure)
// C[M,N] = A[M,K] * W[N,K]^T + bias. 128 x BN tile, BK=64, gload_lds staging.
// EPI: 0 = bias -> bf16 ; 2 = bias + fp32 residual -> fp32
// BIAS_ROW: bias indexed by output row. QSCALE: cols < N/2 scaled by 0.125 (exact in bf16).
template<int BN, int EPI, int BIAS_ROW, int QSCALE>
static __device__ __forceinline__ void gemm_body(unsigned short* As, unsigned short* Bs,
                                                 const unsigned short* __restrict__ A,
                                                 const unsigned short* __restrict__ W,
                                                 const float* __restrict__ bias,
                                                 const float* __restrict__ resid,
                                                 unsigned short* __restrict__ outb,
                                                 float* __restrict__ outf,
                                                 int M, int N, int K, int bx, int by) {
    constexpr int NI = BN / 32;
    const int t = threadIdx.x, lane = t & 63, w = t >> 6;
    const int m0 = by * 128, n0 = bx * BN;
    const int wm = (w & 1) * 64;
    const int wn = (BN == 128) ? (w >> 1) * 64 : (w >> 1) * 32;
    const int l15 = lane & 15, l4 = lane >> 4;
    const int ar0 = w * 8 + (lane >> 3);
    const int ac0 = (lane & 7) * 8;

    f32x4 acc[4][NI];
    f32x4 z4 = {0.f, 0.f, 0.f, 0.f};
    #pragma unroll
    for (int i = 0; i < 4; i++)
        #pragma unroll
        for (int j = 0; j < NI; j++) acc[i][j] = z4;

    const unsigned short* Ap = A + (size_t)m0 * K;
    const unsigned short* Wp = W + (size_t)n0 * K;

    for (int k0 = 0; k0 < K; k0 += 64) {
        #pragma unroll
        for (int j = 0; j < 4; j++)
            gload16(Ap + (size_t)(j*32 + ar0) * K + k0 + ac0, &As[(j*4 + w) * 512]);
        #pragma unroll
        for (int j = 0; j < BN/32; j++)
            gload16(Wp + (size_t)(j*32 + ar0) * K + k0 + ac0, &Bs[(j*4 + w) * 512]);
        __syncthreads();

        #pragma unroll
        for (int ks = 0; ks < 2; ks++) {
            bf16x8 af[4], bfr[NI];
            #pragma unroll
            for (int mi = 0; mi < 4; mi++)
                af[mi] = *(const bf16x8*)&As[(wm + mi*16 + l15)*64 + ks*32 + l4*8];
            #pragma unroll
            for (int ni = 0; ni < NI; ni++)
                bfr[ni] = *(const bf16x8*)&Bs[(wn + ni*16 + l15)*64 + ks*32 + l4*8];
            #pragma unroll
            for (int mi = 0; mi < 4; mi++)
                #pragma unroll
                for (int ni = 0; ni < NI; ni++)
                    acc[mi][ni] = __builtin_amdgcn_mfma_f32_16x16x32_bf16(af[mi], bfr[ni], acc[mi][ni], 0, 0, 0);
        }
        __syncthreads();
    }

    #pragma unroll
    for (int mi = 0; mi < 4; mi++) {
        #pragma unroll
        for (int ni = 0; ni < NI; ni++) {
            int gc = n0 + wn + ni*16 + l15;
            float bc = BIAS_ROW ? 0.f : bias[gc];
            #pragma unroll
            for (int j = 0; j < 4; j++) {
                int gr = m0 + wm + mi*16 + 4*l4 + j;
                float val = acc[mi][ni][j] + (BIAS_ROW ? bias[gr] : bc);
                if (QSCALE) { if (gc < (N >> 1)) val *= 0.125f; }  // Q pre-scale (exact in bf16)
                if (EPI == 2) {
                    val += resid[(size_t)gr * N + gc];
                    outf[(size_t)gr * N + gc] = val;
                } else {
                    outb[(size_t)gr * N + gc] = f2bf(val);
                }
            }
        }
    }
}

// standalone 2-phase GEMM (o-proj, FFN2) with XCD remap
template<int BN, int EPI, int BIAS_ROW, int QSCALE>
__global__ __launch_bounds__(256) void gemm_bt(const unsigned short* __restrict__ A,
                                               const unsigned short* __restrict__ W,
                                               const float* __restrict__ bias,
                                               const float* __restrict__ resid,
                                               unsigned short* __restrict__ outb,
                                               float* __restrict__ outf,
                                               int M, int N, int K) {
    __shared__ __align__(16) unsigned short As[128 * 64];
    __shared__ __align__(16) unsigned short Bs[BN * 64];
    const int nwg  = gridDim.x * gridDim.y;
    const int orig = blockIdx.y * gridDim.x + blockIdx.x;
    const int wg   = (orig & 7) * (nwg >> 3) + (orig >> 3);
    const int bx   = wg % gridDim.x, by = wg / gridDim.x;
    gemm_body<BN,EPI,BIAS_ROW,QSCALE>(As, Bs, A, W, bias, resid, outb, outf, M, N, K, bx, by);
}

// merged QK-projection + transposed-V projection: 1024 wgs -> ~4 wg/CU (implicit overlap)
__global__ __launch_bounds__(256) void qkv_kernel(const unsigned short* __restrict__ xn,
                                                  const unsigned short* __restrict__ wqkb,
                                                  const float* __restrict__ bqk,
                                                  const unsigned short* __restrict__ wvb,
                                                  const float* __restrict__ bv,
                                                  unsigned short* __restrict__ qkb,
                                                  unsigned short* __restrict__ vtb) {
    __shared__ __align__(16) unsigned short As[128 * 64];
    __shared__ __align__(16) unsigned short Bs[128 * 64];
    int orig = blockIdx.x;
    if (orig < 512) {
        // QK: [4096,2048] = xn * [wq|wk]^T, BN=128, gx=16 gy=32
        int wg = (orig & 7) * 64 + (orig >> 3);
        int bx = wg & 15, by = wg >> 4;
        gemm_body<128,0,0,1>(As, Bs, xn, wqkb, bqk, nullptr, qkb, nullptr, MROWS, 2048, D_, bx, by);
    } else {
        // vT: [1024,4096] = Wv * Xn^T (row bias), BN=64, gx=64 gy=8
        int o2 = orig - 512;
        int wg = (o2 & 7) * 64 + (o2 >> 3);
        int bx = wg & 63, by = wg >> 6;
        gemm_body<64,0,1,0>(As, Bs, wvb, xn, bv, nullptr, vtb, nullptr, D_, MROWS, D_, bx, by);
    }
}

// ---------------------------------------------------------------- 8-phase-style 256x256 GEMM (FFN1)
// 8 waves (512 thr), BK=64, double-buffered 128KB LDS, counted vmcnt(8) across RAW
// barriers, 4 MFMA phases per K-tile with setprio, XOR slot-swizzle (both-sides).
// EPI: 1 = bias+ReLU -> bf16
template<int EPI>
__global__ __launch_bounds__(512) void gemm256(const unsigned short* __restrict__ A,
                                               const unsigned short* __restrict__ W,
                                               const float* __restrict__ bias,
                                               unsigned short* __restrict__ outb,
                                               int M, int N, int K) {
    __shared__ __align__(16) unsigned short Asm[2][256 * 64];   // 64 KB
    __shared__ __align__(16) unsigned short Bsm[2][256 * 64];   // 64 KB
    const int t = threadIdx.x, lane = t & 63, w = t >> 6;
    const int l15 = lane & 15, l4 = lane >> 4;
    const int nwg  = gridDim.x;
    const int orig = blockIdx.x;
    const int wg   = (orig & 7) * (nwg >> 3) + (orig >> 3);
    const int gx = N >> 8;
    const int bx = wg % gx, by = wg / gx;
    const int m0 = by << 8, n0 = bx << 8;
    const int wr = w >> 2, wc = w & 3;           // wave: M-half, N-quarter (128x64 out)
    const int srow  = t >> 3;                    // staging row 0..63 (+j*64)
    const int sslot = (t & 7) ^ (srow & 7);      // pre-swizzled source 16B-slot
    const unsigned short* Ap = A + (size_t)m0 * K + sslot * 8;
    const unsigned short* Wp = W + (size_t)n0 * K + sslot * 8;
    const int ldsb = (w * 8) * 64;               // wave-uniform LDS base (+ j*4096)
    const int rsw = (l15 & 7);                   // read-side swizzle bits

    f32x4 acc[8][4];
    f32x4 z4 = {0.f, 0.f, 0.f, 0.f};
    #pragma unroll
    for (int i = 0; i < 8; i++)
        #pragma unroll
        for (int j = 0; j < 4; j++) acc[i][j] = z4;

    const int NT = K >> 6;
    #pragma unroll
    for (int j = 0; j < 4; j++) gload16(Ap + (size_t)(j*64 + srow) * K, &Asm[0][j*4096 + ldsb]);
    #pragma unroll
    for (int j = 0; j < 4; j++) gload16(Wp + (size_t)(j*64 + srow) * K, &Bsm[0][j*4096 + ldsb]);

    for (int T = 0; T < NT; T++) {
        unsigned short* Ab = Asm[T & 1];
        unsigned short* Bb = Bsm[T & 1];
        if (T + 1 < NT) {
            const size_t k0 = (size_t)(T + 1) << 6;
            unsigned short* An = Asm[(T + 1) & 1];
            unsigned short* Bn = Bsm[(T + 1) & 1];
            #pragma unroll
            for (int j = 0; j < 4; j++) gload16(Ap + (size_t)(j*64 + srow) * K + k0, &An[j*4096 + ldsb]);
            #pragma unroll
            for (int j = 0; j < 4; j++) gload16(Wp + (size_t)(j*64 + srow) * K + k0, &Bn[j*4096 + ldsb]);
            asm volatile("s_waitcnt vmcnt(8)" ::: "memory");   // tile T landed; T+1's 8 stay in flight
        } else {
            asm volatile("s_waitcnt vmcnt(0)" ::: "memory");
        }
        __builtin_amdgcn_sched_barrier(0);
        __builtin_amdgcn_s_barrier();
        __builtin_amdgcn_sched_barrier(0);

        bf16x8 af[8][2];   // A-frags for the whole K-tile (register-persistent)
        #pragma unroll
        for (int mi = 0; mi < 8; mi++)
            #pragma unroll
            for (int kk = 0; kk < 2; kk++)
                af[mi][kk] = *(const bf16x8*)&Ab[(wr*128 + mi*16 + l15)*64 + (((4*kk + l4) ^ rsw) * 8)];
        #pragma unroll
        for (int p = 0; p < 4; p++) {
            const int brow = (wc*64 + p*16 + l15)*64;
            bf16x8 bf0 = *(const bf16x8*)&Bb[brow + (((0 + l4) ^ rsw) * 8)];
            bf16x8 bf1 = *(const bf16x8*)&Bb[brow + (((4 + l4) ^ rsw) * 8)];
            __builtin_amdgcn_s_setprio(1);
            #pragma unroll
            for (int mi = 0; mi < 8; mi++) {
                acc[mi][p] = __builtin_amdgcn_mfma_f32_16x16x32_bf16(af[mi][0], bf0, acc[mi][p], 0, 0, 0);
                acc[mi][p] = __builtin_amdgcn_mfma_f32_16x16x32_bf16(af[mi][1], bf1, acc[mi][p], 0, 0, 0);
            }
            __builtin_amdgcn_s_setprio(0);
            __builtin_amdgcn_sched_barrier(0);
            __builtin_amdgcn_s_barrier();
            __builtin_amdgcn_sched_barrier(0);
        }
    }

    #pragma unroll
    for (int p = 0; p < 4; p++) {
        int gc = n0 + wc*64 + p*16 + l15;
        float bv = bias[gc];
        #pragma unroll
        for (int mi = 0; mi < 8; mi++) {
            #pragma unroll
            for (int j = 0; j < 4; j++) {
                int gr = m0 + wr*128 + mi*16 + l4*4 + j;
                float val = acc[mi][p][j] + bv;
                if (EPI == 1) val = fmaxf(val, 0.f);
                outb[(size_t)gr * N + gc] = f2bf(val);
            }
        }
    }
}

// ---------------------------------------------------------------- flash attention (swapped QK^T + T14 async-stage)
// grid: (S/64, B*H); block 256 (4 waves). Q pre-scaled by 0.125 (exact). __expf softmax.
// T14: next tile's K/V/mask loaded into regs right after the staging barrier; the
// L2 latency hides under QK+softmax+PV; ds_writes happen at next iteration top.
__global__ __launch_bounds__(256) void attn_kernel(const unsigned short* __restrict__ qk,
                                                   const unsigned short* __restrict__ vt,
                                                   const int* __restrict__ mask,
                                                   unsigned short* __restrict__ out) {
    __shared__ __align__(16) unsigned short Ks[64*64], Vs[64*64], Ps[64*64];
    __shared__ float mF[64];
    const int t = threadIdx.x, lane = t & 63, w = t >> 6;
    const int l15 = lane & 15, l4 = lane >> 4;
    const int bh = blockIdx.y, b = bh >> 4, h = bh & 15;
    const int q0 = blockIdx.x * 64;
    const unsigned short* qb  = qk + ((size_t)(b * S_ + q0)) * 2048 + h * DK_;
    const unsigned short* kb  = qk + ((size_t)(b * S_)) * 2048 + 1024 + h * DK_;
    const unsigned short* vtb = vt + (size_t)(h * DK_) * MROWS + (size_t)b * S_;

    bf16x8 aq[2];
    #pragma unroll
    for (int ks = 0; ks < 2; ks++)
        aq[ks] = *(const bf16x8*)(qb + (size_t)(w*16 + l15) * 2048 + ks*32 + l4*8);

    float m_ = -INFINITY, l_ = 0.f;
    f32x4 accd[4];
    f32x4 z4 = {0.f, 0.f, 0.f, 0.f};
    #pragma unroll
    for (int dt = 0; dt < 4; dt++) accd[dt] = z4;

    const int r_  = t >> 3, c8_ = (t & 7) * 8;
    const int cs_ = c8_ ^ ((r_ & 7) << 3);
    const int rsw = (l15 & 7) << 3;

    // T14 prologue: tile 0 into regs
    uint4 kreg[2], vreg[2];
    float mreg = 0.f;
    #pragma unroll
    for (int p2 = 0; p2 < 2; p2++) {
        int r = r_ + p2 * 32;
        kreg[p2] = *(const uint4*)(kb  + (size_t)r * 2048 + c8_);
        vreg[p2] = *(const uint4*)(vtb + (size_t)r * MROWS + c8_);
    }
    if (t < 64) mreg = (mask[(size_t)b * S_ + t] == 0) ? -1e9f : 0.f;

    for (int kv0 = 0; kv0 < S_; kv0 += 64) {
        // write staged regs to LDS (swizzled)
        #pragma unroll
        for (int p2 = 0; p2 < 2; p2++) {
            int r = r_ + p2 * 32;
            *(uint4*)&Ks[r*64 + cs_] = kreg[p2];
            *(uint4*)&Vs[r*64 + cs_] = vreg[p2];
        }
        if (t < 64) mF[t] = mreg;
        __syncthreads();

        // T14: issue next tile loads now; consumed at next iteration's ds_writes
        int kn = kv0 + 64;
        if (kn < S_) {
            #pragma unroll
            for (int p2 = 0; p2 < 2; p2++) {
                int r = r_ + p2 * 32;
                kreg[p2] = *(const uint4*)(kb  + (size_t)(kn + r) * 2048 + c8_);
                vreg[p2] = *(const uint4*)(vtb + (size_t)r * MROWS + kn + c8_);
            }
            if (t < 64) mreg = (mask[(size_t)b * S_ + kn + t] == 0) ? -1e9f : 0.f;
        }

        // scores SWAPPED: sc[nt][j] = S[key = nt*16 + 4*l4 + j][q = w*16 + l15]
        f32x4 sc[4];
        #pragma unroll
        for (int nt = 0; nt < 4; nt++) sc[nt] = z4;
        #pragma unroll
        for (int nt = 0; nt < 4; nt++)
            #pragma unroll
            for (int ks = 0; ks < 2; ks++) {
                bf16x8 kf = *(const bf16x8*)&Ks[(nt*16 + l15)*64 + ((ks*32 + 8*l4) ^ rsw)];
                sc[nt] = __builtin_amdgcn_mfma_f32_16x16x32_bf16(kf, aq[ks], sc[nt], 0, 0, 0);
            }

        float sv[4][4];
        #pragma unroll
        for (int nt = 0; nt < 4; nt++) {
            float4 ma = *(const float4*)&mF[nt*16 + 4*l4];
            sv[nt][0] = sc[nt][0] + ma.x;
            sv[nt][1] = sc[nt][1] + ma.y;
            sv[nt][2] = sc[nt][2] + ma.z;
            sv[nt][3] = sc[nt][3] + ma.w;
        }

        float mt = fmaxf(fmaxf(fmaxf(sv[0][0], sv[0][1]), fmaxf(sv[0][2], sv[0][3])),
                         fmaxf(fmaxf(sv[1][0], sv[1][1]), fmaxf(sv[1][2], sv[1][3])));
        mt = fmaxf(mt, fmaxf(fmaxf(fmaxf(sv[2][0], sv[2][1]), fmaxf(sv[2][2], sv[2][3])),
                             fmaxf(fmaxf(sv[3][0], sv[3][1]), fmaxf(sv[3][2], sv[3][3]))));
        mt = fmaxf(mt, __shfl_xor(mt, 16));
        mt = fmaxf(mt, __shfl_xor(mt, 32));

        if (__any(mt > m_)) {
            float mn  = fmaxf(m_, mt);
            float esc = __expf(m_ - mn);
            m_ = mn;
            l_ *= esc;
            float ea[4];
            #pragma unroll
            for (int j = 0; j < 4; j++) ea[j] = __shfl(esc, 4*l4 + j);
            #pragma unroll
            for (int dt = 0; dt < 4; dt++)
                #pragma unroll
                for (int j = 0; j < 4; j++) accd[dt][j] *= ea[j];
        }

        float p[4][4];
        float rsum = 0.f;
        #pragma unroll
        for (int nt = 0; nt < 4; nt++)
            #pragma unroll
            for (int j = 0; j < 4; j++) { p[nt][j] = __expf(sv[nt][j] - m_); rsum += p[nt][j]; }
        rsum += __shfl_xor(rsum, 16);
        rsum += __shfl_xor(rsum, 32);
        l_ += rsum;

        #pragma unroll
        for (int nt = 0; nt < 4; nt++) {
            uint2 w2;
            w2.x = (unsigned)f2bf(p[nt][0]) | ((unsigned)f2bf(p[nt][1]) << 16);
            w2.y = (unsigned)f2bf(p[nt][2]) | ((unsigned)f2bf(p[nt][3]) << 16);
            int key0 = nt*16 + 4*l4;
            *(uint2*)&Ps[(w*16 + l15)*64 + (key0 ^ rsw)] = w2;
        }

        bf16x8 pa[2];
        #pragma unroll
        for (int ks = 0; ks < 2; ks++)
            pa[ks] = *(const bf16x8*)&Ps[(w*16 + l15)*64 + ((ks*32 + 8*l4) ^ rsw)];
        #pragma unroll
        for (int dt = 0; dt < 4; dt++)
            #pragma unroll
            for (int ks = 0; ks < 2; ks++) {
                bf16x8 vv8 = *(const bf16x8*)&Vs[(dt*16 + l15)*64 + ((ks*32 + 8*l4) ^ rsw)];
                accd[dt] = __builtin_amdgcn_mfma_f32_16x16x32_bf16(pa[ks], vv8, accd[dt], 0, 0, 0);
            }
        __syncthreads();
    }

    float inv = 1.f / l_;
    float ia[4];
    #pragma unroll
    for (int j = 0; j < 4; j++) ia[j] = __shfl(inv, 4*l4 + j);
    unsigned short* ob = out + ((size_t)(b * S_ + q0)) * D_ + h * DK_;
    #pragma unroll
    for (int j = 0; j < 4; j++) {
        int r = w*16 + 4*l4 + j;
        #pragma unroll
        for (int dt = 0; dt < 4; dt++)
            ob[(size_t)r * D_ + dt*16 + l15] = f2bf(accd[dt][j] * ia[j]);
    }
}

// ---------------------------------------------------------------- launch
extern "C" void kernel_launch(void* const* d_in, const int* in_sizes, int n_in,
                              void* d_out, int out_size, void* d_ws, size_t ws_size,
                              hipStream_t stream) {
    const float* x    = (const float*)d_in[0];
    const int*   mask = (const int*)d_in[1];
    const float* wq = (const float*)d_in[2];
    const float* bq = (const float*)d_in[3];
    const float* wk = (const float*)d_in[4];
    const float* bk = (const float*)d_in[5];
    const float* wv = (const float*)d_in[6];
    const float* bv = (const float*)d_in[7];
    const float* wo = (const float*)d_in[8];
    const float* bo = (const float*)d_in[9];
    const float* w1 = (const float*)d_in[10];
    const float* b1 = (const float*)d_in[11];
    const float* w2 = (const float*)d_in[12];
    const float* b2 = (const float*)d_in[13];
    const float* a1  = (const float*)d_in[14];
    const float* be1 = (const float*)d_in[15];
    const float* a2  = (const float*)d_in[16];
    const float* be2 = (const float*)d_in[17];
    float* out = (float*)d_out;

    // workspace layout (80 MB): see prior rounds
    char* ws = (char*)d_ws;
    unsigned short* wqkb = (unsigned short*)(ws + (0ull  << 20));
    unsigned short* wvb  = (unsigned short*)(ws + (4ull  << 20));
    unsigned short* wob  = (unsigned short*)(ws + (6ull  << 20));
    unsigned short* w1b  = (unsigned short*)(ws + (8ull  << 20));
    unsigned short* w2b  = (unsigned short*)(ws + (16ull << 20));
    unsigned short* xn   = (unsigned short*)(ws + (24ull << 20));
    unsigned short* qkb  = (unsigned short*)(ws + (32ull << 20));
    unsigned short* vtb  = (unsigned short*)(ws + (48ull << 20));
    float*          bqk  = (float*)         (ws + (60ull << 20));
    unsigned short* hh   = qkb;              // 32MB region reused after attn
    float*          x1   = (float*)(ws + (64ull << 20));

    dim3 blk(256);

    prep_kernel<<<12289, blk, 0, stream>>>(wq, wk, wv, wo, w1, w2, bq, bk,
                                           wqkb, wvb, wob, w1b, w2b, bqk);

    ln_kernel<<<MROWS, blk, 0, stream>>>(x, a1, be1, xn);

    // merged QK projection (Q pre-scaled 0.125) + transposed V projection
    qkv_kernel<<<1024, blk, 0, stream>>>(xn, wqkb, bqk, wvb, bv, qkb, vtb);

    dim3 ga(S_/64, B_*H_);          // (32, 32)
    attn_kernel<<<ga, blk, 0, stream>>>(qkb, vtb, mask, xn);   // attn_out -> xn

    // o-proj + residual -> fp32 x1
    dim3 go(D_/64, MROWS/128);      // (16, 32)
    gemm_bt<64,2,0,0><<<go, blk, 0, stream>>>(xn, wob, bo, x, nullptr, x1, MROWS, D_, D_);

    ln_kernel<<<MROWS, blk, 0, stream>>>(x1, a2, be2, xn);     // xn2 -> xn

    // FFN1 (ReLU): [4096,4096] x [4096,1024]^T — 8-phase 256² kernel, 256 wgs
    gemm256<1><<<256, 512, 0, stream>>>(xn, w1b, b1, hh, MROWS, DFF_, D_);

    // FFN2 + residual -> fp32 out
    gemm_bt<64,2,0,0><<<go, blk, 0, stream>>>(hh, w2b, b2, x1, nullptr, out, MROWS, D_, DFF_);
}

// Round 10
// 398.432 us; speedup vs baseline: 1.2202x; 1.2202x over previous
//
#include <hip/hip_runtime.h>

// Problem constants
#define B_    2
#define S_    2048
#define D_    1024
#define H_    16
#define DK_   64
#define DFF_  4096
#define MROWS (B_*S_)   // 4096 rows

typedef float f32x4 __attribute__((ext_vector_type(4)));
typedef __bf16 bf16x8 __attribute__((ext_vector_type(8)));

static __device__ __forceinline__ unsigned short f2bf(float f) {
    union { __bf16 h; unsigned short u; } cv;
    cv.h = (__bf16)f;
    return cv.u;
}

// async global->LDS, 16B per lane; LDS base must be wave-uniform (HW: base + lane*16)
static __device__ __forceinline__ void gload16(const unsigned short* g, unsigned short* l) {
    __builtin_amdgcn_global_load_lds((const __attribute__((address_space(1))) void*)g,
                                     (__attribute__((address_space(3))) void*)l, 16, 0, 0);
}

// ---------------------------------------------------------------- prep: all weight casts + bias concat (1 launch)
__global__ __launch_bounds__(256) void prep_kernel(
    const float* __restrict__ wq, const float* __restrict__ wk,
    const float* __restrict__ wv, const float* __restrict__ wo,
    const float* __restrict__ w1, const float* __restrict__ w2,
    const float* __restrict__ bq, const float* __restrict__ bk,
    unsigned short* __restrict__ wqkb, unsigned short* __restrict__ wvb,
    unsigned short* __restrict__ wob, unsigned short* __restrict__ w1b,
    unsigned short* __restrict__ w2b, float* __restrict__ bqk) {
    int blk = blockIdx.x;
    if (blk >= 12288) {               // bias concat: bqk[0..1023]=bq, [1024..2047]=bk
        int t0 = threadIdx.x * 8;
        #pragma unroll
        for (int i = 0; i < 8; i++) {
            int j = t0 + i;
            bqk[j] = (j < 1024) ? bq[j] : bk[j - 1024];
        }
        return;
    }
    const float* src; unsigned short* dst; int lb;
    if      (blk < 1024) { src = wq; dst = wqkb;             lb = blk;        }
    else if (blk < 2048) { src = wk; dst = wqkb + (1 << 20); lb = blk - 1024; }
    else if (blk < 3072) { src = wv; dst = wvb;              lb = blk - 2048; }
    else if (blk < 4096) { src = wo; dst = wob;              lb = blk - 3072; }
    else if (blk < 8192) { src = w1; dst = w1b;              lb = blk - 4096; }
    else                 { src = w2; dst = w2b;              lb = blk - 8192; }
    int i4 = lb * 256 + threadIdx.x;
    float4 v = ((const float4*)src)[i4];
    ushort4 o;
    o.x = f2bf(v.x); o.y = f2bf(v.y); o.z = f2bf(v.z); o.w = f2bf(v.w);
    ((ushort4*)dst)[i4] = o;
}

// ---------------------------------------------------------------- LayerNorm (ddof=1, /(std+eps))
__global__ __launch_bounds__(256) void ln_kernel(const float* __restrict__ x,
                                                 const float* __restrict__ alphap,
                                                 const float* __restrict__ betap,
                                                 unsigned short* __restrict__ out) {
    int row = blockIdx.x;
    int t = threadIdx.x;
    const float* xr = x + (size_t)row * D_;
    float4 v = ((const float4*)xr)[t];
    float s  = v.x + v.y + v.z + v.w;
    float s2 = v.x*v.x + v.y*v.y + v.z*v.z + v.w*v.w;
    #pragma unroll
    for (int o = 1; o < 64; o <<= 1) { s += __shfl_xor(s, o); s2 += __shfl_xor(s2, o); }
    __shared__ float ss[4], ss2[4];
    if ((t & 63) == 0) { ss[t >> 6] = s; ss2[t >> 6] = s2; }
    __syncthreads();
    float S  = ss[0] + ss[1] + ss[2] + ss[3];
    float S2 = ss2[0] + ss2[1] + ss2[2] + ss2[3];
    float mean = S * (1.f / (float)D_);
    float var  = (S2 - S * mean) / (float)(D_ - 1);   // unbiased (ddof=1)
    float alpha = alphap[0], beta = betap[0];
    float inv = alpha / (sqrtf(fmaxf(var, 0.f)) + 1e-6f);
    ushort4 o4;
    o4.x = f2bf((v.x - mean) * inv + beta);
    o4.y = f2bf((v.y - mean) * inv + beta);
    o4.z = f2bf((v.z - mean) * inv + beta);
    o4.w = f2bf((v.w - mean) * inv + beta);
    ((ushort4*)(out + (size_t)row * D_))[t] = o4;
}

// ---------------------------------------------------------------- 2-phase GEMM body (m97 structure)
// C[M,N] = A[M,K] * W[N,K]^T + bias. 128 x BN tile, BK=64, gload_lds staging.
// EPI: 0 = bias -> bf16 ; 2 = bias + fp32 residual -> fp32
// BIAS_ROW: bias indexed by output row. QSCALE: cols < N/2 scaled by 0.125 (exact in bf16).
template<int BN, int EPI, int BIAS_ROW, int QSCALE>
static __device__ __forceinline__ void gemm_body(unsigned short* As, unsigned short* Bs,
                                                 const unsigned short* __restrict__ A,
                                                 const unsigned short* __restrict__ W,
                                                 const float* __restrict__ bias,
                                                 const float* __restrict__ resid,
                                                 unsigned short* __restrict__ outb,
                                                 float* __restrict__ outf,
                                                 int M, int N, int K, int bx, int by) {
    constexpr int NI = BN / 32;
    const int t = threadIdx.x, lane = t & 63, w = t >> 6;
    const int m0 = by * 128, n0 = bx * BN;
    const int wm = (w & 1) * 64;
    const int wn = (BN == 128) ? (w >> 1) * 64 : (w >> 1) * 32;
    const int l15 = lane & 15, l4 = lane >> 4;
    const int ar0 = w * 8 + (lane >> 3);
    const int ac0 = (lane & 7) * 8;

    f32x4 acc[4][NI];
    f32x4 z4 = {0.f, 0.f, 0.f, 0.f};
    #pragma unroll
    for (int i = 0; i < 4; i++)
        #pragma unroll
        for (int j = 0; j < NI; j++) acc[i][j] = z4;

    const unsigned short* Ap = A + (size_t)m0 * K;
    const unsigned short* Wp = W + (size_t)n0 * K;

    for (int k0 = 0; k0 < K; k0 += 64) {
        #pragma unroll
        for (int j = 0; j < 4; j++)
            gload16(Ap + (size_t)(j*32 + ar0) * K + k0 + ac0, &As[(j*4 + w) * 512]);
        #pragma unroll
        for (int j = 0; j < BN/32; j++)
            gload16(Wp + (size_t)(j*32 + ar0) * K + k0 + ac0, &Bs[(j*4 + w) * 512]);
        __syncthreads();

        #pragma unroll
        for (int ks = 0; ks < 2; ks++) {
            bf16x8 af[4], bfr[NI];
            #pragma unroll
            for (int mi = 0; mi < 4; mi++)
                af[mi] = *(const bf16x8*)&As[(wm + mi*16 + l15)*64 + ks*32 + l4*8];
            #pragma unroll
            for (int ni = 0; ni < NI; ni++)
                bfr[ni] = *(const bf16x8*)&Bs[(wn + ni*16 + l15)*64 + ks*32 + l4*8];
            #pragma unroll
            for (int mi = 0; mi < 4; mi++)
                #pragma unroll
                for (int ni = 0; ni < NI; ni++)
                    acc[mi][ni] = __builtin_amdgcn_mfma_f32_16x16x32_bf16(af[mi], bfr[ni], acc[mi][ni], 0, 0, 0);
        }
        __syncthreads();
    }

    #pragma unroll
    for (int mi = 0; mi < 4; mi++) {
        #pragma unroll
        for (int ni = 0; ni < NI; ni++) {
            int gc = n0 + wn + ni*16 + l15;
            float bc = BIAS_ROW ? 0.f : bias[gc];
            #pragma unroll
            for (int j = 0; j < 4; j++) {
                int gr = m0 + wm + mi*16 + 4*l4 + j;
                float val = acc[mi][ni][j] + (BIAS_ROW ? bias[gr] : bc);
                if (QSCALE) { if (gc < (N >> 1)) val *= 0.125f; }  // Q pre-scale (exact in bf16)
                if (EPI == 2) {
                    val += resid[(size_t)gr * N + gc];
                    outf[(size_t)gr * N + gc] = val;
                } else {
                    outb[(size_t)gr * N + gc] = f2bf(val);
                }
            }
        }
    }
}

// standalone 2-phase GEMM (o-proj, FFN2) with XCD remap
template<int BN, int EPI, int BIAS_ROW, int QSCALE>
__global__ __launch_bounds__(256) void gemm_bt(const unsigned short* __restrict__ A,
                                               const unsigned short* __restrict__ W,
                                               const float* __restrict__ bias,
                                               const float* __restrict__ resid,
                                               unsigned short* __restrict__ outb,
                                               float* __restrict__ outf,
                                               int M, int N, int K) {
    __shared__ __align__(16) unsigned short As[128 * 64];
    __shared__ __align__(16) unsigned short Bs[BN * 64];
    const int nwg  = gridDim.x * gridDim.y;
    const int orig = blockIdx.y * gridDim.x + blockIdx.x;
    const int wg   = (orig & 7) * (nwg >> 3) + (orig >> 3);
    const int bx   = wg % gridDim.x, by = wg / gridDim.x;
    gemm_body<BN,EPI,BIAS_ROW,QSCALE>(As, Bs, A, W, bias, resid, outb, outf, M, N, K, bx, by);
}

// merged QK-projection + transposed-V projection: 1024 wgs -> ~4 wg/CU (implicit overlap)
__global__ __launch_bounds__(256) void qkv_kernel(const unsigned short* __restrict__ xn,
                                                  const unsigned short* __restrict__ wqkb,
                                                  const float* __restrict__ bqk,
                                                  const unsigned short* __restrict__ wvb,
                                                  const float* __restrict__ bv,
                                                  unsigned short* __restrict__ qkb,
                                                  unsigned short* __restrict__ vtb) {
    __shared__ __align__(16) unsigned short As[128 * 64];
    __shared__ __align__(16) unsigned short Bs[128 * 64];
    int orig = blockIdx.x;
    if (orig < 512) {
        // QK: [4096,2048] = xn * [wq|wk]^T, BN=128, gx=16 gy=32
        int wg = (orig & 7) * 64 + (orig >> 3);
        int bx = wg & 15, by = wg >> 4;
        gemm_body<128,0,0,1>(As, Bs, xn, wqkb, bqk, nullptr, qkb, nullptr, MROWS, 2048, D_, bx, by);
    } else {
        // vT: [1024,4096] = Wv * Xn^T (row bias), BN=64, gx=64 gy=8
        int o2 = orig - 512;
        int wg = (o2 & 7) * 64 + (o2 >> 3);
        int bx = wg & 63, by = wg >> 6;
        gemm_body<64,0,1,0>(As, Bs, wvb, xn, bv, nullptr, vtb, nullptr, D_, MROWS, D_, bx, by);
    }
}

// ---------------------------------------------------------------- 8-phase-style 256x256 GEMM (FFN1)
// 8 waves (512 thr), BK=64, double-buffered 128KB LDS, counted vmcnt(8) across RAW
// barriers, 4 MFMA phases per K-tile with setprio, XOR slot-swizzle (both-sides).
// EPI: 1 = bias+ReLU -> bf16
template<int EPI>
__global__ __launch_bounds__(512) void gemm256(const unsigned short* __restrict__ A,
                                               const unsigned short* __restrict__ W,
                                               const float* __restrict__ bias,
                                               unsigned short* __restrict__ outb,
                                               int M, int N, int K) {
    __shared__ __align__(16) unsigned short Asm[2][256 * 64];   // 64 KB
    __shared__ __align__(16) unsigned short Bsm[2][256 * 64];   // 64 KB
    const int t = threadIdx.x, lane = t & 63, w = t >> 6;
    const int l15 = lane & 15, l4 = lane >> 4;
    const int nwg  = gridDim.x;
    const int orig = blockIdx.x;
    const int wg   = (orig & 7) * (nwg >> 3) + (orig >> 3);
    const int gx = N >> 8;
    const int bx = wg % gx, by = wg / gx;
    const int m0 = by << 8, n0 = bx << 8;
    const int wr = w >> 2, wc = w & 3;           // wave: M-half, N-quarter (128x64 out)
    const int srow  = t >> 3;                    // staging row 0..63 (+j*64)
    const int sslot = (t & 7) ^ (srow & 7);      // pre-swizzled source 16B-slot
    const unsigned short* Ap = A + (size_t)m0 * K + sslot * 8;
    const unsigned short* Wp = W + (size_t)n0 * K + sslot * 8;
    const int ldsb = (w * 8) * 64;               // wave-uniform LDS base (+ j*4096)
    const int rsw = (l15 & 7);                   // read-side swizzle bits

    f32x4 acc[8][4];
    f32x4 z4 = {0.f, 0.f, 0.f, 0.f};
    #pragma unroll
    for (int i = 0; i < 8; i++)
        #pragma unroll
        for (int j = 0; j < 4; j++) acc[i][j] = z4;

    const int NT = K >> 6;
    #pragma unroll
    for (int j = 0; j < 4; j++) gload16(Ap + (size_t)(j*64 + srow) * K, &Asm[0][j*4096 + ldsb]);
    #pragma unroll
    for (int j = 0; j < 4; j++) gload16(Wp + (size_t)(j*64 + srow) * K, &Bsm[0][j*4096 + ldsb]);

    for (int T = 0; T < NT; T++) {
        unsigned short* Ab = Asm[T & 1];
        unsigned short* Bb = Bsm[T & 1];
        if (T + 1 < NT) {
            const size_t k0 = (size_t)(T + 1) << 6;
            unsigned short* An = Asm[(T + 1) & 1];
            unsigned short* Bn = Bsm[(T + 1) & 1];
            #pragma unroll
            for (int j = 0; j < 4; j++) gload16(Ap + (size_t)(j*64 + srow) * K + k0, &An[j*4096 + ldsb]);
            #pragma unroll
            for (int j = 0; j < 4; j++) gload16(Wp + (size_t)(j*64 + srow) * K + k0, &Bn[j*4096 + ldsb]);
            asm volatile("s_waitcnt vmcnt(8)" ::: "memory");   // tile T landed; T+1's 8 stay in flight
        } else {
            asm volatile("s_waitcnt vmcnt(0)" ::: "memory");
        }
        __builtin_amdgcn_sched_barrier(0);
        __builtin_amdgcn_s_barrier();
        __builtin_amdgcn_sched_barrier(0);

        bf16x8 af[8][2];   // A-frags for the whole K-tile (register-persistent)
        #pragma unroll
        for (int mi = 0; mi < 8; mi++)
            #pragma unroll
            for (int kk = 0; kk < 2; kk++)
                af[mi][kk] = *(const bf16x8*)&Ab[(wr*128 + mi*16 + l15)*64 + (((4*kk + l4) ^ rsw) * 8)];
        #pragma unroll
        for (int p = 0; p < 4; p++) {
            const int brow = (wc*64 + p*16 + l15)*64;
            bf16x8 bf0 = *(const bf16x8*)&Bb[brow + (((0 + l4) ^ rsw) * 8)];
            bf16x8 bf1 = *(const bf16x8*)&Bb[brow + (((4 + l4) ^ rsw) * 8)];
            __builtin_amdgcn_s_setprio(1);
            #pragma unroll
            for (int mi = 0; mi < 8; mi++) {
                acc[mi][p] = __builtin_amdgcn_mfma_f32_16x16x32_bf16(af[mi][0], bf0, acc[mi][p], 0, 0, 0);
                acc[mi][p] = __builtin_amdgcn_mfma_f32_16x16x32_bf16(af[mi][1], bf1, acc[mi][p], 0, 0, 0);
            }
            __builtin_amdgcn_s_setprio(0);
            __builtin_amdgcn_sched_barrier(0);
            __builtin_amdgcn_s_barrier();
            __builtin_amdgcn_sched_barrier(0);
        }
    }

    #pragma unroll
    for (int p = 0; p < 4; p++) {
        int gc = n0 + wc*64 + p*16 + l15;
        float bv = bias[gc];
        #pragma unroll
        for (int mi = 0; mi < 8; mi++) {
            #pragma unroll
            for (int j = 0; j < 4; j++) {
                int gr = m0 + wr*128 + mi*16 + l4*4 + j;
                float val = acc[mi][p][j] + bv;
                if (EPI == 1) val = fmaxf(val, 0.f);
                outb[(size_t)gr * N + gc] = f2bf(val);
            }
        }
    }
}

// ---------------------------------------------------------------- flash attention (swapped QK^T, direct staging)
// grid: (S/64, B*H); block 256 (4 waves). Q pre-scaled 0.125 (exact). __expf softmax.
// Direct global->LDS staging (loads consumed immediately — no long live ranges, no spill;
// the r9 T14 reg-staging variant spilled to scratch: WRITE_SIZE 8MB -> 316MB. Do not re-add
// without a localMem check). T13 defer-max THR=8: skip rescale unless row max grew > 8.
__global__ __launch_bounds__(256) void attn_kernel(const unsigned short* __restrict__ qk,
                                                   const unsigned short* __restrict__ vt,
                                                   const int* __restrict__ mask,
                                                   unsigned short* __restrict__ out) {
    __shared__ __align__(16) unsigned short Ks[64*64], Vs[64*64], Ps[64*64];
    __shared__ float mF[64];
    const int t = threadIdx.x, lane = t & 63, w = t >> 6;
    const int l15 = lane & 15, l4 = lane >> 4;
    const int bh = blockIdx.y, b = bh >> 4, h = bh & 15;
    const int q0 = blockIdx.x * 64;
    const unsigned short* qb  = qk + ((size_t)(b * S_ + q0)) * 2048 + h * DK_;
    const unsigned short* kb  = qk + ((size_t)(b * S_)) * 2048 + 1024 + h * DK_;
    const unsigned short* vtb = vt + (size_t)(h * DK_) * MROWS + (size_t)b * S_;

    // hoisted Q fragments (loop-invariant; Q already scaled by 1/8).
    bf16x8 aq[2];
    #pragma unroll
    for (int ks = 0; ks < 2; ks++)
        aq[ks] = *(const bf16x8*)(qb + (size_t)(w*16 + l15) * 2048 + ks*32 + l4*8);

    float m_ = -INFINITY, l_ = 0.f;   // softmax state for q-row l15 (lane-local)
    f32x4 accd[4];                    // O[q=4*l4+j][d=dt*16+l15]
    f32x4 z4 = {0.f, 0.f, 0.f, 0.f};
    #pragma unroll
    for (int dt = 0; dt < 4; dt++) accd[dt] = z4;

    const int r_  = t >> 3, c8_ = (t & 7) * 8;       // staging rows 0..31 (+32)
    const int cs_ = c8_ ^ ((r_ & 7) << 3);           // swizzled staging col
    const int rsw = (l15 & 7) << 3;                  // read-side swizzle (row&7 == l15&7)

    for (int kv0 = 0; kv0 < S_; kv0 += 64) {
        // stage K (row=key) and V^T (row=d) — coalesced uint4, swizzled LDS
        #pragma unroll
        for (int p2 = 0; p2 < 2; p2++) {
            int r = r_ + p2 * 32;
            *(uint4*)&Ks[r*64 + cs_] = *(const uint4*)(kb  + (size_t)(kv0 + r) * 2048 + c8_);
            *(uint4*)&Vs[r*64 + cs_] = *(const uint4*)(vtb + (size_t)r * MROWS + kv0 + c8_);
        }
        if (t < 64) mF[t] = (mask[(size_t)b * S_ + kv0 + t] == 0) ? -1e9f : 0.f;
        __syncthreads();

        // scores SWAPPED: sc[nt][j] = S[key = nt*16 + 4*l4 + j][q = w*16 + l15]
        f32x4 sc[4];
        #pragma unroll
        for (int nt = 0; nt < 4; nt++) sc[nt] = z4;
        #pragma unroll
        for (int nt = 0; nt < 4; nt++)
            #pragma unroll
            for (int ks = 0; ks < 2; ks++) {
                bf16x8 kf = *(const bf16x8*)&Ks[(nt*16 + l15)*64 + ((ks*32 + 8*l4) ^ rsw)];
                sc[nt] = __builtin_amdgcn_mfma_f32_16x16x32_bf16(kf, aq[ks], sc[nt], 0, 0, 0);
            }

        // additive mask by key (broadcast float4 reads)
        float sv[4][4];
        #pragma unroll
        for (int nt = 0; nt < 4; nt++) {
            float4 ma = *(const float4*)&mF[nt*16 + 4*l4];
            sv[nt][0] = sc[nt][0] + ma.x;
            sv[nt][1] = sc[nt][1] + ma.y;
            sv[nt][2] = sc[nt][2] + ma.z;
            sv[nt][3] = sc[nt][3] + ma.w;
        }

        // row max: in-register over 16 values, then 2 shfl_xor across l4 group
        float mt = fmaxf(fmaxf(fmaxf(sv[0][0], sv[0][1]), fmaxf(sv[0][2], sv[0][3])),
                         fmaxf(fmaxf(sv[1][0], sv[1][1]), fmaxf(sv[1][2], sv[1][3])));
        mt = fmaxf(mt, fmaxf(fmaxf(fmaxf(sv[2][0], sv[2][1]), fmaxf(sv[2][2], sv[2][3])),
                             fmaxf(fmaxf(sv[3][0], sv[3][1]), fmaxf(sv[3][2], sv[3][3]))));
        mt = fmaxf(mt, __shfl_xor(mt, 16));
        mt = fmaxf(mt, __shfl_xor(mt, 32));

        // T13 defer-max: only rescale when some row's max grew by > 8 (P bounded by e^8)
        if (__any(mt > m_ + 8.f)) {
            float mn  = fmaxf(m_, mt);
            float esc = __expf(m_ - mn);   // ==1 for rows that didn't grow
            m_ = mn;
            l_ *= esc;
            float ea[4];
            #pragma unroll
            for (int j = 0; j < 4; j++) ea[j] = __shfl(esc, 4*l4 + j);
            #pragma unroll
            for (int dt = 0; dt < 4; dt++)
                #pragma unroll
                for (int j = 0; j < 4; j++) accd[dt][j] *= ea[j];
        }

        // P = exp(S - m) with lane-local m; row sum in-register + 2 shfl
        float p[4][4];
        float rsum = 0.f;
        #pragma unroll
        for (int nt = 0; nt < 4; nt++)
            #pragma unroll
            for (int j = 0; j < 4; j++) { p[nt][j] = __expf(sv[nt][j] - m_); rsum += p[nt][j]; }
        rsum += __shfl_xor(rsum, 16);
        rsum += __shfl_xor(rsum, 32);
        l_ += rsum;

        // write P: 4 packed ds_write_b64 (keys nt*16+4*l4 .. +3 adjacent), swizzled
        #pragma unroll
        for (int nt = 0; nt < 4; nt++) {
            uint2 w2;
            w2.x = (unsigned)f2bf(p[nt][0]) | ((unsigned)f2bf(p[nt][1]) << 16);
            w2.y = (unsigned)f2bf(p[nt][2]) | ((unsigned)f2bf(p[nt][3]) << 16);
            int key0 = nt*16 + 4*l4;
            *(uint2*)&Ps[(w*16 + l15)*64 + (key0 ^ rsw)] = w2;
        }

        // PV: O += P[16x64] * V[64x64]
        bf16x8 pa[2];
        #pragma unroll
        for (int ks = 0; ks < 2; ks++)
            pa[ks] = *(const bf16x8*)&Ps[(w*16 + l15)*64 + ((ks*32 + 8*l4) ^ rsw)];
        #pragma unroll
        for (int dt = 0; dt < 4; dt++)
            #pragma unroll
            for (int ks = 0; ks < 2; ks++) {
                bf16x8 vv8 = *(const bf16x8*)&Vs[(dt*16 + l15)*64 + ((ks*32 + 8*l4) ^ rsw)];
                accd[dt] = __builtin_amdgcn_mfma_f32_16x16x32_bf16(pa[ks], vv8, accd[dt], 0, 0, 0);
            }
        __syncthreads();   // protect Ks/Vs/mF before next-iter staging
    }

    // epilogue: 1/l at q=l15 -> q=4*l4+j via 4 bpermute
    float inv = 1.f / l_;
    float ia[4];
    #pragma unroll
    for (int j = 0; j < 4; j++) ia[j] = __shfl(inv, 4*l4 + j);
    unsigned short* ob = out + ((size_t)(b * S_ + q0)) * D_ + h * DK_;
    #pragma unroll
    for (int j = 0; j < 4; j++) {
        int r = w*16 + 4*l4 + j;
        #pragma unroll
        for (int dt = 0; dt < 4; dt++)
            ob[(size_t)r * D_ + dt*16 + l15] = f2bf(accd[dt][j] * ia[j]);
    }
}

// ---------------------------------------------------------------- launch
extern "C" void kernel_launch(void* const* d_in, const int* in_sizes, int n_in,
                              void* d_out, int out_size, void* d_ws, size_t ws_size,
                              hipStream_t stream) {
    const float* x    = (const float*)d_in[0];
    const int*   mask = (const int*)d_in[1];
    const float* wq = (const float*)d_in[2];
    const float* bq = (const float*)d_in[3];
    const float* wk = (const float*)d_in[4];
    const float* bk = (const float*)d_in[5];
    const float* wv = (const float*)d_in[6];
    const float* bv = (const float*)d_in[7];
    const float* wo = (const float*)d_in[8];
    const float* bo = (const float*)d_in[9];
    const float* w1 = (const float*)d_in[10];
    const float* b1 = (const float*)d_in[11];
    const float* w2 = (const float*)d_in[12];
    const float* b2 = (const float*)d_in[13];
    const float* a1  = (const float*)d_in[14];
    const float* be1 = (const float*)d_in[15];
    const float* a2  = (const float*)d_in[16];
    const float* be2 = (const float*)d_in[17];
    float* out = (float*)d_out;

    // workspace layout (80 MB): see prior rounds
    char* ws = (char*)d_ws;
    unsigned short* wqkb = (unsigned short*)(ws + (0ull  << 20));
    unsigned short* wvb  = (unsigned short*)(ws + (4ull  << 20));
    unsigned short* wob  = (unsigned short*)(ws + (6ull  << 20));
    unsigned short* w1b  = (unsigned short*)(ws + (8ull  << 20));
    unsigned short* w2b  = (unsigned short*)(ws + (16ull << 20));
    unsigned short* xn   = (unsigned short*)(ws + (24ull << 20));
    unsigned short* qkb  = (unsigned short*)(ws + (32ull << 20));
    unsigned short* vtb  = (unsigned short*)(ws + (48ull << 20));
    float*          bqk  = (float*)         (ws + (60ull << 20));
    unsigned short* hh   = qkb;              // 32MB region reused after attn
    float*          x1   = (float*)(ws + (64ull << 20));

    dim3 blk(256);

    prep_kernel<<<12289, blk, 0, stream>>>(wq, wk, wv, wo, w1, w2, bq, bk,
                                           wqkb, wvb, wob, w1b, w2b, bqk);

    ln_kernel<<<MROWS, blk, 0, stream>>>(x, a1, be1, xn);

    // merged QK projection (Q pre-scaled 0.125) + transposed V projection
    qkv_kernel<<<1024, blk, 0, stream>>>(xn, wqkb, bqk, wvb, bv, qkb, vtb);

    dim3 ga(S_/64, B_*H_);          // (32, 32)
    attn_kernel<<<ga, blk, 0, stream>>>(qkb, vtb, mask, xn);   // attn_out -> xn

    // o-proj + residual -> fp32 x1
    dim3 go(D_/64, MROWS/128);      // (16, 32)
    gemm_bt<64,2,0,0><<<go, blk, 0, stream>>>(xn, wob, bo, x, nullptr, x1, MROWS, D_, D_);

    ln_kernel<<<MROWS, blk, 0, stream>>>(x1, a2, be2, xn);     // xn2 -> xn

    // FFN1 (ReLU): [4096,4096] x [4096,1024]^T — 8-phase 256² kernel, 256 wgs
    gemm256<1><<<256, 512, 0, stream>>>(xn, w1b, b1, hh, MROWS, DFF_, D_);

    // FFN2 + residual -> fp32 out
    gemm_bt<64,2,0,0><<<go, blk, 0, stream>>>(hh, w2b, b2, x1, nullptr, out, MROWS, D_, DFF_);
}